// Round 7
// baseline (41.862 us; speedup 1.0000x reference)
//
#include <hip/hip_runtime.h>
#include <stdint.h>

typedef unsigned int u32;

#define NACC   31
#define NSHIFT 15
#define ROWB   4096     // bytes per (c,b) row: 2048 positions * 2 planes
#define NBLK   512      // 512 blocks * 4 waves = 2048 waves, exactly 2 blocks/CU
#define RPW    4        // rows per wave (2048 * 4 = 8192 rows)
#define NSH    32       // shadow copies of each counter

typedef __attribute__((address_space(3))) unsigned char lds_u8;
typedef __attribute__((address_space(1))) const unsigned char gbl_u8;

// 16 input bytes = positions q..q+7, byte 2i = plane0(q+i), 2i+1 = plane1(q+i).
// Appends 8 bits to P0 (plane0) and P1 (plane1) at bit offset 8t.
// 0/1-byte->bit: (b0|b1<<8|b2<<16|b3<<24) * 0x01020408 puts b0..b3 at bits
// 24..27 carry-free.
__device__ __forceinline__ void pack16(uint4 v, u32& P0, u32& P1, int t) {
    const u32 q0 = __byte_perm(v.x, v.y, 0x6420);  // plane0, +0..3
    const u32 q1 = __byte_perm(v.x, v.y, 0x7531);  // plane1, +0..3
    const u32 q2 = __byte_perm(v.z, v.w, 0x6420);  // plane0, +4..7
    const u32 q3 = __byte_perm(v.z, v.w, 0x7531);  // plane1, +4..7
    const u32 n0 = (q0 * 0x01020408u) >> 24;
    const u32 n1 = (q1 * 0x01020408u) >> 24;
    const u32 n2 = (q2 * 0x01020408u) >> 24;
    const u32 n3 = (q3 * 0x01020408u) >> 24;
    P0 |= (n0 | (n2 << 4)) << (8 * t);
    P1 |= (n1 | (n3 << 4)) << (8 * t);
}

// DMA-pipelined wave-per-row kernel.
// Each wave owns a private 16 KB LDS buffer (4 arrays x 4 KB raw row bytes),
// filled by global_load_lds (fully coalesced 1 KB/instr, no VGPR staging).
// Schedule per row: vmcnt(0) -> ds_read+pack (consumes LDS) -> issue next
// row's 16 DMA loads -> 31-shift popcount block. Waves are memory-paced;
// the 2/SIMD occupancy plus 16 outstanding DMA loads per wave keep the
// memory system saturated with coalesced requests.
// Lane l owns positions 32l..32l+31 per plane; ring = the 64-lane wave;
// |s|<=15 < 32 so rotations need only lane+-1 words.
// No device-scope fences (round-4 lesson: per-block __threadfence on CDNA4
// = L2 writeback storm, 10x slowdown).
__global__ __launch_bounds__(256, 2) void hd_main(
    const unsigned char* __restrict__ ia, const unsigned char* __restrict__ ma,
    const unsigned char* __restrict__ ib, const unsigned char* __restrict__ mb,
    u32* __restrict__ cnt)
{
    const int tid  = threadIdx.x;
    const int lane = tid & 63;
    const int wv   = tid >> 6;
    const int gw   = blockIdx.x * 4 + wv;        // 0..2047

    __shared__ alignas(16) union {
        unsigned char stg[4][4][4096];           // [wave][array][row bytes]
        u32 red[32][132];                        // tail reduction scratch
    } sh;

#define STAGE_ARR(X, gp) do {                                               \
        _Pragma("unroll")                                                   \
        for (int k_ = 0; k_ < 4; ++k_) {                                    \
            __builtin_amdgcn_global_load_lds(                               \
                (const gbl_u8*)((gp) + k_ * 1024 + lane * 16),              \
                (lds_u8*)&sh.stg[wv][X][k_ * 1024], 16, 0, 0);              \
        }                                                                   \
    } while (0)

#define STAGE_ROW(rb) do {                                                  \
        const size_t rb_ = (rb);                                            \
        STAGE_ARR(0, ia + rb_);                                             \
        STAGE_ARR(1, ma + rb_);                                             \
        STAGE_ARR(2, ib + rb_);                                             \
        STAGE_ARR(3, mb + rb_);                                             \
    } while (0)

#define LOADPACK(X, P0, P1) do {                                            \
        P0 = 0u; P1 = 0u;                                                   \
        _Pragma("unroll")                                                   \
        for (int j_ = 0; j_ < 4; ++j_) {                                    \
            const uint4 v_ = *(const uint4*)&sh.stg[wv][X][lane * 64 + j_ * 16]; \
            pack16(v_, P0, P1, j_);                                         \
        }                                                                   \
    } while (0)

    const int prevL = (lane + 63) & 63;
    const int nextL = (lane + 1) & 63;

    u32 acc[NACC];                               // num | den<<16 per shift
#pragma unroll
    for (int j = 0; j < NACC; ++j) acc[j] = 0u;

    const size_t rowbase0 = (size_t)gw * RPW * ROWB;
    STAGE_ROW(rowbase0);                         // prologue: row 0 in flight

#pragma unroll
    for (int r = 0; r < RPW; ++r) {
        // wait for this row's 16 DMA loads to land in LDS
        asm volatile("s_waitcnt vmcnt(0)" ::: "memory");
        __builtin_amdgcn_sched_barrier(0);

        // consume the buffer: ds_read_b128 own 64B per array, pack to bits
        u32 A0, A1, M0, M1, B0, B1, N0, N1;
        LOADPACK(0, A0, A1);
        LOADPACK(1, M0, M1);
        LOADPACK(2, B0, B1);
        LOADPACK(3, N0, N1);
        __builtin_amdgcn_sched_barrier(0);

        // buffer free -> queue next row's DMA under the shift block
        if (r + 1 < RPW) STAGE_ROW(rowbase0 + (size_t)(r + 1) * ROWB);

        // neighbors + 31 rotations (pure VALU)
        const u32 pA0 = __shfl(A0, prevL, 64), pA1 = __shfl(A1, prevL, 64);
        const u32 pM0 = __shfl(M0, prevL, 64), pM1 = __shfl(M1, prevL, 64);
        const u32 nA0 = __shfl(A0, nextL, 64), nA1 = __shfl(A1, nextL, 64);
        const u32 nM0 = __shfl(M0, nextL, 64), nM1 = __shfl(M1, nextL, 64);

        {   // s = 0 (j = 15)
            const u32 k0 = M0 & N0, k1 = M1 & N1;
            const u32 nm = __popc((A0 ^ B0) & k0) + __popc((A1 ^ B1) & k1);
            const u32 dn = __popc(k0) + __popc(k1);
            acc[15] += nm | (dn << 16);
        }
#pragma unroll
        for (int s = 1; s <= NSHIFT; ++s) {
            {   // roll right by s: rolled[p] = orig[p-s]  (j = 15+s)
                const u32 ra0 = (A0 << s) | (pA0 >> (32 - s));
                const u32 ra1 = (A1 << s) | (pA1 >> (32 - s));
                const u32 rm0 = (M0 << s) | (pM0 >> (32 - s));
                const u32 rm1 = (M1 << s) | (pM1 >> (32 - s));
                const u32 k0 = rm0 & N0, k1 = rm1 & N1;
                const u32 nm = __popc((ra0 ^ B0) & k0) + __popc((ra1 ^ B1) & k1);
                const u32 dn = __popc(k0) + __popc(k1);
                acc[15 + s] += nm | (dn << 16);
            }
            {   // roll left by s: rolled[p] = orig[p+s]   (j = 15-s)
                const u32 ra0 = (A0 >> s) | (nA0 << (32 - s));
                const u32 ra1 = (A1 >> s) | (nA1 << (32 - s));
                const u32 rm0 = (M0 >> s) | (nM0 << (32 - s));
                const u32 rm1 = (M1 >> s) | (nM1 << (32 - s));
                const u32 k0 = rm0 & N0, k1 = rm1 & N1;
                const u32 nm = __popc((ra0 ^ B0) & k0) + __popc((ra1 ^ B1) & k1);
                const u32 dn = __popc(k0) + __popc(k1);
                acc[15 - s] += nm | (dn << 16);
            }
        }
    }

    // ---- tail: reuse staging LDS as reduction scratch ----
    // per-lane fields <= 4*64 = 256; after the 32-xor <= 512; block partial
    // sums (8 thr/j x 16 packed values <= 8192) unpacked before combining.
    __syncthreads();     // all waves done reading their staging buffers
#pragma unroll
    for (int j = 0; j < NACC; ++j) acc[j] += __shfl_xor(acc[j], 32, 64);
#pragma unroll
    for (int j = 0; j < NACC; j += 2) {
        const u32 v = (j + 1 < NACC && (lane & 32)) ? acc[j + 1] : acc[j];
        sh.red[j + (lane >> 5)][wv * 32 + (lane & 31)] = v;
    }
    __syncthreads();

    if (tid < 248) {
        const int j = tid >> 3, c = tid & 7;     // 8 threads per counter j
        const uint4* p = (const uint4*)&sh.red[j][c * 16];
        u32 sn = 0, sd = 0;
#pragma unroll
        for (int i = 0; i < 4; ++i) {
            const uint4 v = p[i];
            sn += (v.x & 0xFFFFu) + (v.y & 0xFFFFu) + (v.z & 0xFFFFu) + (v.w & 0xFFFFu);
            sd += (v.x >> 16) + (v.y >> 16) + (v.z >> 16) + (v.w >> 16);
        }
        sn += __shfl_xor(sn, 1, 64); sd += __shfl_xor(sd, 1, 64);
        sn += __shfl_xor(sn, 2, 64); sd += __shfl_xor(sd, 2, 64);
        sn += __shfl_xor(sn, 4, 64); sd += __shfl_xor(sd, 4, 64);
        if (c == 0) {
            const int shd = blockIdx.x & (NSH - 1);
            atomicAdd(&cnt[j * NSH + shd], sn);          // num_j
            atomicAdd(&cnt[(31 + j) * NSH + shd], sd);   // den_j
        }
    }
    // no fence: device-scope atomics + kernel boundary order the finalize.
}

// One block, 256 threads: fold 32 shadows per counter (vector loads),
// 31 divisions, min, clamp to 1.
__global__ void hd_finalize(const u32* __restrict__ cnt, float* __restrict__ out)
{
    __shared__ u32 gathered[62];
    const int tid = threadIdx.x;
    if (tid < 248) {
        const int j = tid >> 2, q = tid & 3;     // 4 threads per counter
        const uint4* p = (const uint4*)&cnt[j * NSH + q * 8];
        const uint4 v0 = p[0], v1 = p[1];
        u32 s = v0.x + v0.y + v0.z + v0.w + v1.x + v1.y + v1.z + v1.w;
        s += __shfl_xor(s, 1, 64);
        s += __shfl_xor(s, 2, 64);
        if (q == 0) gathered[j] = s;
    }
    __syncthreads();
    if (tid < 64) {
        float f = 1.0f;
        if (tid < NACC) f = (float)gathered[tid] / (float)gathered[31 + tid];
#pragma unroll
        for (int o = 32; o > 0; o >>= 1) f = fminf(f, __shfl_xor(f, o, 64));
        if (tid == 0) out[0] = fminf(f, 1.0f);
    }
}

extern "C" void kernel_launch(void* const* d_in, const int* in_sizes, int n_in,
                              void* d_out, int out_size, void* d_ws, size_t ws_size,
                              hipStream_t stream)
{
    const unsigned char* ia = (const unsigned char*)d_in[0];  // iris_codes_a
    const unsigned char* ma = (const unsigned char*)d_in[1];  // mask_codes_a
    const unsigned char* ib = (const unsigned char*)d_in[2];  // iris_codes_b
    const unsigned char* mb = (const unsigned char*)d_in[3];  // mask_codes_b
    u32* cnt = (u32*)d_ws;                    // [62][32] shadow counters

    hipMemsetAsync(d_ws, 0, 62 * NSH * sizeof(u32), stream);
    hd_main<<<dim3(NBLK), dim3(256), 0, stream>>>(ia, ma, ib, mb, cnt);
    hd_finalize<<<dim3(1), dim3(256), 0, stream>>>(cnt, (float*)d_out);
}